// Round 11
// baseline (922.427 us; speedup 1.0000x reference)
//
#include <hip/hip_runtime.h>
#include <math.h>

#define N_NODES 10000
#define N_EDGES 80000
#define N_GRAPH 64
#define DD 64
#define HIDW 128
#define F_IN 14
#define EAD 4

typedef _Float16 f16x8 __attribute__((ext_vector_type(8)));
typedef float f32x4 __attribute__((ext_vector_type(4)));

__device__ __forceinline__ float sigmoidf_(float x){ return 1.0f/(1.0f+expf(-x)); }

// ---------- fused prep: Bpack + weight transposes + count + graphoff + lin0 ----------
__global__ __launch_bounds__(256) void k_prep_misc(
    const float* __restrict__ h2w, _Float16* __restrict__ Bp,
    const float* __restrict__ gih, const float* __restrict__ ghh,
    const float* __restrict__ lih, const float* __restrict__ lhh,
    float* __restrict__ WihT, float* __restrict__ WhhT,
    float* __restrict__ IhT,  float* __restrict__ HhT,
    const int* __restrict__ tgt, int* __restrict__ cnt,
    const int* __restrict__ batch, int* __restrict__ goff,
    const float* __restrict__ x, const float* __restrict__ l0w,
    const float* __restrict__ l0b, float* __restrict__ s)
{
  int idx = blockIdx.x*256 + threadIdx.x;
  if (idx < 524288){
    int j = idx & 7, l = (idx >> 3) & 63, cg = (idx >> 9) & 3, st = idx >> 11;
    int k = st*32 + ((l >> 4) << 3) + j;
    int h = k >> 6, i = k & 63, o = cg*16 + (l & 15);
    Bp[idx] = (_Float16)h2w[(size_t)h*4096 + i*64 + o];
    return;
  }
  idx -= 524288;
  if (idx < 12288){ int k=idx/192, j=idx%192; WihT[idx]=gih[j*64+k]; return; }
  idx -= 12288;
  if (idx < 12288){ int k=idx/192, j=idx%192; WhhT[idx]=ghh[j*64+k]; return; }
  idx -= 12288;
  if (idx < 32768){ int k=idx>>8, j=idx&255; IhT[idx]=lih[j*128+k]; return; }
  idx -= 32768;
  if (idx < 16384){ int k=idx>>8, j=idx&255; HhT[idx]=lhh[j*64+k]; return; }
  idx -= 16384;
  if (idx < N_EDGES){ atomicAdd(&cnt[tgt[idx]], 1); return; }
  idx -= N_EDGES;
  if (idx < 65){
    int g = idx, lo = 0, hi = N_NODES;
    while (lo < hi){ int mid = (lo+hi)>>1; if (batch[mid] < g) lo = mid+1; else hi = mid; }
    goff[g] = lo; return;
  }
  idx -= 65;
  if (idx < N_NODES*64){
    int n = idx >> 6, o = idx & 63;
    float acc = l0b[o];
    #pragma unroll
    for (int k=0;k<F_IN;++k) acc += x[n*F_IN + k]*l0w[k*64 + o];
    s[idx] = fmaxf(acc, 0.f);
    return;
  }
}
#define PREP_TOT (524288 + 12288 + 12288 + 32768 + 16384 + N_EDGES + 65 + N_NODES*64)

// ---------- CSR build ----------

__global__ __launch_bounds__(1024) void k_scan(const int* __restrict__ cnt, int* __restrict__ offs,
                                               int* __restrict__ cursor, float* __restrict__ deginv){
  __shared__ int sc[1024];
  int t = threadIdx.x;
  int base = t*10;
  int loc[10]; int tot = 0;
  #pragma unroll
  for (int j=0;j<10;++j){
    int i = base+j;
    int c = (i < N_NODES) ? cnt[i] : 0;
    loc[j] = tot; tot += c;
  }
  sc[t] = tot; __syncthreads();
  for (int st=1; st<1024; st<<=1){
    int v = (t>=st) ? sc[t-st] : 0;
    __syncthreads();
    sc[t] += v;
    __syncthreads();
  }
  int ex = sc[t] - tot;
  #pragma unroll
  for (int j=0;j<10;++j){
    int i = base+j;
    if (i < N_NODES){
      int o = ex + loc[j];
      offs[i] = o; cursor[i] = o;
      int c = cnt[i];
      deginv[i] = 1.0f/(float)(c > 0 ? c : 1);
    }
  }
  if (t == 1023) offs[N_NODES] = sc[1023];
}

__global__ void k_sortE(const int* __restrict__ tgt, const int* __restrict__ src,
                        int* __restrict__ cursor, int* __restrict__ srcS, int* __restrict__ pos){
  int e = blockIdx.x*256 + threadIdx.x;
  if (e < N_EDGES){
    int p = atomicAdd(&cursor[tgt[e]], 1);
    srcS[p] = src[e];
    pos[e] = p;
  }
}

// hid = relu(ea@h1+b1), iteration-invariant; write in SORTED edge order (fp16)
__global__ __launch_bounds__(256) void k_hid(const float* __restrict__ ea,
    const float* __restrict__ h1_w, const float* __restrict__ h1_b,
    const int* __restrict__ pos, _Float16* __restrict__ hidS){
  int tid = threadIdx.x;
  int g = tid >> 7, j = tid & 127;
  __shared__ float eL[2][EAD];
  __shared__ int pL[2];
  if (tid < 8){ int gg = tid>>2, k = tid&3; eL[gg][k] = ea[(blockIdx.x*2+gg)*EAD + k]; }
  if (tid < 2) pL[tid] = pos[blockIdx.x*2 + tid];
  __syncthreads();
  float v = h1_b[j];
  #pragma unroll
  for (int k=0;k<EAD;++k) v += eL[g][k]*h1_w[k*HIDW + j];
  hidS[(size_t)pL[g]*HIDW + j] = (_Float16)fmaxf(v, 0.f);
}

// ---------- stage 1: P build for node chunk [n0, n0+grid) ----------
__global__ __launch_bounds__(256) void k_aggpre(
    const float* __restrict__ s, const _Float16* __restrict__ hidS,
    const int* __restrict__ offs, const int* __restrict__ srcS,
    _Float16* __restrict__ P, float* __restrict__ Ssum, int n0){
  int t = n0 + blockIdx.x;
  int tid = threadIdx.x;
  int i8 = tid & 7, hb = tid >> 3;
  __shared__ float sL[8][64];
  __shared__ float hidT[8][128];
  float acc[4][8];
  #pragma unroll
  for (int r=0;r<4;++r)
    #pragma unroll
    for (int ii=0;ii<8;++ii) acc[r][ii] = 0.f;
  float ss[8];
  #pragma unroll
  for (int ii=0;ii<8;++ii) ss[ii] = 0.f;
  int e0 = offs[t], e1 = offs[t+1];
  for (int base = e0; base < e1; base += 8){
    int ecnt = min(8, e1 - base);
    __syncthreads();
    for (int a = tid; a < ecnt*64; a += 256){
      int j = a >> 6, ii = a & 63;
      sL[j][ii] = s[(size_t)srcS[base+j]*64 + ii];
    }
    for (int a = tid; a < ecnt*128; a += 256){
      int j = a >> 7, hh = a & 127;
      hidT[j][(hh & 3)*32 + (hh >> 2)] = (float)hidS[(size_t)(base+j)*HIDW + hh];
    }
    __syncthreads();
    for (int j=0;j<ecnt;++j){
      float hv[4], sv[8];
      #pragma unroll
      for (int r=0;r<4;++r) hv[r] = hidT[j][r*32 + hb];
      #pragma unroll
      for (int ii=0;ii<8;++ii) sv[ii] = sL[j][i8*8 + ii];
      #pragma unroll
      for (int r=0;r<4;++r)
        #pragma unroll
        for (int ii=0;ii<8;++ii) acc[r][ii] += hv[r]*sv[ii];
      if (hb == 0){
        #pragma unroll
        for (int ii=0;ii<8;++ii) ss[ii] += sv[ii];
      }
    }
  }
  _Float16* row = P + (size_t)blockIdx.x*8192;
  #pragma unroll
  for (int r=0;r<4;++r){
    f16x8 pk;
    #pragma unroll
    for (int ii=0;ii<8;++ii) pk[ii] = (_Float16)acc[r][ii];
    *(f16x8*)(row + (hb*4 + r)*64 + i8*8) = pk;
  }
  if (hb == 0){
    float4 v0 = make_float4(ss[0],ss[1],ss[2],ss[3]);
    float4 v1 = make_float4(ss[4],ss[5],ss[6],ss[7]);
    *(float4*)(Ssum + (size_t)t*64 + i8*8)     = v0;
    *(float4*)(Ssum + (size_t)t*64 + i8*8 + 4) = v1;
  }
}

// ---------- stage 2 + node update fused, BK=512, LDS overlay (33 KB) ----------
// Block = 16 rows of chunk. Reads sOld, writes sNew (double-buffered s).
__global__ __launch_bounds__(256) void k_gemm_fused(
    const _Float16* __restrict__ A, const _Float16* __restrict__ Bp,
    const float* __restrict__ Ssum, const float* __restrict__ h2b,
    const float* __restrict__ deginv, const float* __restrict__ sOld,
    float* __restrict__ sNew,
    const float* __restrict__ conv_root, const float* __restrict__ conv_bias,
    const float* __restrict__ WihT, const float* __restrict__ WhhT,
    const float* __restrict__ bih, const float* __restrict__ bhh, int n0)
{
  __shared__ __align__(16) char smem[32768];   // tile[2][16][512] fp16; epilogue overlays tile[0]
  int tid = threadIdx.x;
  int t0 = n0 + blockIdx.x*16;
  const char* Ab = (const char*)A + (size_t)blockIdx.x*16*16384;
  int sub = tid >> 6;
  int colb = (tid & 63) * 16;
  f16x8 rg[4];
  int cg = tid >> 6, lane = tid & 63;
  int row = lane & 15, kb = lane >> 4;
  int swz = (row & 7) << 4;
  f32x4 acc = {0.f,0.f,0.f,0.f};

  // prologue: stage slot 0
  #pragma unroll
  for (int i2=0;i2<4;++i2){
    int r = i2*4 + sub;
    rg[i2] = *(const f16x8*)(Ab + (size_t)r*16384 + (size_t)(colb ^ ((r&7)<<4)));
  }
  #pragma unroll
  for (int i2=0;i2<4;++i2){
    int r = i2*4 + sub;
    *(f16x8*)(smem + r*1024 + colb) = rg[i2];
  }
  for (int y = 0; y < 16; ++y){
    if (y < 15){
      #pragma unroll
      for (int i2=0;i2<4;++i2){
        int r = i2*4 + sub;
        rg[i2] = *(const f16x8*)(Ab + (size_t)r*16384 + (size_t)(y+1)*1024 + (size_t)(colb ^ ((r&7)<<4)));
      }
    }
    __syncthreads();
    const char* tb = smem + (y&1)*16384 + row*1024;
    #pragma unroll 16
    for (int st = 0; st < 16; ++st){
      f16x8 af = *(const f16x8*)(tb + ((st*64 + kb*16) ^ swz));
      f16x8 bf = *(const f16x8*)(Bp + ((size_t)((y*16 + st)*4 + cg)*64 + lane)*8);
      acc = __builtin_amdgcn_mfma_f32_16x16x32_f16(af, bf, acc, 0, 0, 0);
    }
    if (y < 15){
      char* tw = smem + ((y+1)&1)*16384;
      #pragma unroll
      for (int i2=0;i2<4;++i2){
        int r = i2*4 + sub;
        *(f16x8*)(tw + r*1024 + colb) = rg[i2];
      }
    }
  }
  // ---- epilogue (overlays tile[0]; last MFMA slot used tile[1] only) ----
  float* aggL = (float*)smem;            // [16][68]
  float* hSs  = (float*)(smem + 4352);   // [16][64]
  float* xSs  = (float*)(smem + 8448);   // [16][68]  (ssS, later m)
  #pragma unroll
  for (int r=0;r<4;++r) aggL[(kb*4 + r)*68 + cg*16 + row] = acc[r];
  for (int a = tid; a < 1024; a += 256){
    int nn = a >> 6, o2 = a & 63;
    hSs[nn*64 + o2] = sOld[(size_t)(t0+nn)*64 + o2];
    xSs[nn*68 + o2] = Ssum[(size_t)(t0+nn)*64 + o2];
  }
  __syncthreads();
  int o = tid & 63, ng = tid >> 6;   // nodes ng, ng+4, ng+8, ng+12
  float aM[4];
  #pragma unroll
  for (int u=0;u<4;++u) aM[u] = aggL[(ng + 4*u)*68 + o];
  for (int k=0;k<64;++k){
    float w2 = h2b[k*64 + o];
    #pragma unroll
    for (int u=0;u<4;++u) aM[u] += xSs[(ng + 4*u)*68 + k]*w2;
  }
  #pragma unroll
  for (int u=0;u<4;++u) aM[u] = aM[u]*deginv[t0 + ng + 4*u] + conv_bias[o];
  for (int k=0;k<64;++k){
    float cr = conv_root[k*64 + o];
    #pragma unroll
    for (int u=0;u<4;++u) aM[u] += hSs[(ng + 4*u)*64 + k]*cr;
  }
  float mM[4];
  #pragma unroll
  for (int u=0;u<4;++u) mM[u] = fmaxf(aM[u], 0.f);
  __syncthreads();
  #pragma unroll
  for (int u=0;u<4;++u) xSs[(ng + 4*u)*68 + o] = mM[u];
  __syncthreads();
  float gi0[4], gi1[4], gi2[4], gh0[4], gh1[4], gh2[4];
  #pragma unroll
  for (int u=0;u<4;++u){
    gi0[u] = bih[o];     gh0[u] = bhh[o];
    gi1[u] = bih[64+o];  gh1[u] = bhh[64+o];
    gi2[u] = bih[128+o]; gh2[u] = bhh[128+o];
  }
  for (int k=0;k<64;++k){
    float wi0 = WihT[k*192 + o], wi1 = WihT[k*192 + 64 + o], wi2 = WihT[k*192 + 128 + o];
    float wh0 = WhhT[k*192 + o], wh1 = WhhT[k*192 + 64 + o], wh2 = WhhT[k*192 + 128 + o];
    #pragma unroll
    for (int u=0;u<4;++u){
      float mk = xSs[(ng + 4*u)*68 + k], hk = hSs[(ng + 4*u)*64 + k];
      gi0[u] += mk*wi0; gh0[u] += hk*wh0;
      gi1[u] += mk*wi1; gh1[u] += hk*wh1;
      gi2[u] += mk*wi2; gh2[u] += hk*wh2;
    }
  }
  #pragma unroll
  for (int u=0;u<4;++u){
    int nn = ng + 4*u;
    float r = sigmoidf_(gi0[u] + gh0[u]);
    float z = sigmoidf_(gi1[u] + gh1[u]);
    float nv = tanhf(gi2[u] + r*gh2[u]);
    float hnew = (1.f - z)*nv + z*hSs[nn*64 + o];
    sNew[(size_t)(t0+nn)*64 + o] = hnew;
  }
}

// ---------- Set2Set (3 steps) + final MLP, fully fused: one block per graph ----------

__global__ __launch_bounds__(256) void k_s2s_all(const float* __restrict__ sND,
    const int* __restrict__ goff,
    const float* __restrict__ IhT, const float* __restrict__ HhT,
    const float* __restrict__ bih, const float* __restrict__ bhh,
    float* __restrict__ ebuf,
    const float* __restrict__ lin1_w, const float* __restrict__ lin1_b,
    const float* __restrict__ lin2_w, const float* __restrict__ lin2_b,
    float* __restrict__ out)
{
  const int CAP = 256;
  __shared__ float sG[256][68];
  __shared__ float eL[256];
  __shared__ float qL[128], hL[64], cL[64], gate[256];
  __shared__ float red[4], redw[4], red2[4][64];
  int g = blockIdx.x, tid = threadIdx.x;
  int w = tid >> 6, lane = tid & 63;
  int n0 = goff[g], n1 = goff[g+1], cnt = n1 - n0;
  int ncap = cnt < CAP ? cnt : CAP;
  for (int idx = tid; idx < ncap*64; idx += 256)
    sG[idx>>6][idx&63] = sND[(size_t)(n0 + (idx>>6))*64 + (idx&63)];
  if (tid < 128) qL[tid] = 0.f;
  if (tid < 64){ hL[tid] = 0.f; cL[tid] = 0.f; }
  __syncthreads();
  for (int step = 0; step < 3; ++step){
    float acc = bih[tid] + bhh[tid];
    #pragma unroll 8
    for (int k=0;k<128;++k) acc += qL[k]*IhT[k*256 + tid];
    #pragma unroll 8
    for (int k=0;k<64;++k)  acc += hL[k]*HhT[k*256 + tid];
    gate[tid] = acc;
    __syncthreads();
    if (tid < 64){
      float i = sigmoidf_(gate[tid]);
      float f = sigmoidf_(gate[64+tid]);
      float gg = tanhf(gate[128+tid]);
      float o = sigmoidf_(gate[192+tid]);
      float cc = f*cL[tid] + i*gg;
      hL[tid] = o*tanhf(cc);
      cL[tid] = cc;
    }
    __syncthreads();
    float wmax = -INFINITY;
    for (int r = w; r < cnt; r += 4){
      float v = (r < CAP) ? sG[r][lane] : sND[(size_t)(n0+r)*64 + lane];
      float p = v * hL[lane];
      #pragma unroll
      for (int s2=32; s2>0; s2>>=1) p += __shfl_xor(p, s2, 64);
      if (lane == 0){ if (r < CAP) eL[r] = p; else ebuf[n0+r] = p; }
      wmax = fmaxf(wmax, p);
    }
    if (lane == 0) red[w] = wmax;
    __syncthreads();
    float m = fmaxf(fmaxf(red[0], red[1]), fmaxf(red[2], red[3]));
    float racc = 0.f, ws = 0.f;
    for (int r = w; r < cnt; r += 4){
      float e = (r < CAP) ? eL[r] : ebuf[n0+r];
      float a = expf(e - m);
      float v = (r < CAP) ? sG[r][lane] : sND[(size_t)(n0+r)*64 + lane];
      racc += a * v;
      ws += a;
    }
    red2[w][lane] = racc;
    if (lane == 0) redw[w] = ws;
    __syncthreads();
    if (tid < 64){
      float rs = red2[0][lane]+red2[1][lane]+red2[2][lane]+red2[3][lane];
      float st = redw[0]+redw[1]+redw[2]+redw[3];
      float rr = (st > 0.f) ? rs/st : 0.f;
      qL[lane] = hL[lane];
      qL[64+lane] = rr;
    }
    __syncthreads();
  }
  {
    float facc = 0.f;
    for (int k = w*32; k < w*32+32; ++k) facc += qL[k]*lin1_w[k*64 + lane];
    red2[w][lane] = facc;
  }
  __syncthreads();
  if (tid < 64){
    float z = fmaxf(lin1_b[lane] + red2[0][lane]+red2[1][lane]+red2[2][lane]+red2[3][lane], 0.f);
    float p = z * lin2_w[lane];
    #pragma unroll
    for (int s2=32; s2>0; s2>>=1) p += __shfl_xor(p, s2, 64);
    if (lane == 0) out[g] = p + lin2_b[0];
  }
}

// ---------- launch ----------

static inline size_t alignup(size_t x){ return (x + 255) & ~(size_t)255; }

extern "C" void kernel_launch(void* const* d_in, const int* in_sizes, int n_in,
                              void* d_out, int out_size, void* d_ws, size_t ws_size,
                              hipStream_t stream){
  const float* x      = (const float*)d_in[0];
  const int*   ei     = (const int*)  d_in[1];
  const float* ea     = (const float*)d_in[2];
  const int*   batch  = (const int*)  d_in[3];
  const float* lin0_w = (const float*)d_in[5];
  const float* lin0_b = (const float*)d_in[6];
  const float* h1_w   = (const float*)d_in[7];
  const float* h1_b   = (const float*)d_in[8];
  const float* h2_w   = (const float*)d_in[9];
  const float* h2_b   = (const float*)d_in[10];
  const float* conv_root = (const float*)d_in[11];
  const float* conv_bias = (const float*)d_in[12];
  const float* gru_w_ih  = (const float*)d_in[13];
  const float* gru_w_hh  = (const float*)d_in[14];
  const float* gru_b_ih  = (const float*)d_in[15];
  const float* gru_b_hh  = (const float*)d_in[16];
  const float* lstm_w_ih = (const float*)d_in[17];
  const float* lstm_w_hh = (const float*)d_in[18];
  const float* lstm_b_ih = (const float*)d_in[19];
  const float* lstm_b_hh = (const float*)d_in[20];
  const float* lin1_w = (const float*)d_in[21];
  const float* lin1_b = (const float*)d_in[22];
  const float* lin2_w = (const float*)d_in[23];
  const float* lin2_b = (const float*)d_in[24];
  (void)in_sizes; (void)n_in; (void)out_size; (void)ws_size;

  const int* srcA = ei;
  const int* tgtA = ei + N_EDGES;

  // ---- workspace layout (~112 MB) ----
  char* p = (char*)d_ws;
  size_t off = 0;
  auto take = [&](size_t bytes)->char*{ char* q = p + off; off = alignup(off + bytes); return q; };
  _Float16* Bpack = (_Float16*)take((size_t)524288*2);             // 1.05 MB
  float* sbufA    = (float*)take((size_t)N_NODES*DD*4);
  float* sbufB    = (float*)take((size_t)N_NODES*DD*4);
  float* Ssum     = (float*)take((size_t)N_NODES*DD*4);
  _Float16* hidS  = (_Float16*)take((size_t)N_EDGES*HIDW*2);       // 20.48 MB
  float* WihT    = (float*)take(12288*4);
  float* WhhT    = (float*)take(12288*4);
  float* IhT     = (float*)take(32768*4);
  float* HhT     = (float*)take(16384*4);
  float* deginv  = (float*)take(N_NODES*4);
  int*   cnt     = (int*)  take(N_NODES*4);
  int*   offs    = (int*)  take((N_NODES+1)*4);
  int*   cursor  = (int*)  take(N_NODES*4);
  int*   srcS    = (int*)  take(N_EDGES*4);
  int*   pos     = (int*)  take(N_EDGES*4);
  int*   goff    = (int*)  take(65*4);
  float* ebuf    = (float*)take(N_NODES*4);
  _Float16* Pbuf = (_Float16*)take((size_t)5008*8192*2);           // 82.05 MB (reused per chunk)

  hipMemsetAsync(cnt, 0, N_NODES*4, stream);

  k_prep_misc<<<(PREP_TOT + 255)/256, 256, 0, stream>>>(
      h2_w, Bpack, gru_w_ih, gru_w_hh, lstm_w_ih, lstm_w_hh,
      WihT, WhhT, IhT, HhT, tgtA, cnt, batch, goff, x, lin0_w, lin0_b, sbufA);
  k_scan<<<1, 1024, 0, stream>>>(cnt, offs, cursor, deginv);
  k_sortE<<<(N_EDGES+255)/256, 256, 0, stream>>>(tgtA, srcA, cursor, srcS, pos);
  k_hid<<<N_EDGES/2, 256, 0, stream>>>(ea, h1_w, h1_b, pos, hidS);

  float* sCur = sbufA;
  float* sNxt = sbufB;
  const int cb[3] = {0, 4992, 10000};
  for (int it = 0; it < 3; ++it){
    for (int c = 0; c < 2; ++c){
      int nn0 = cb[c], ncnt = cb[c+1] - nn0;
      k_aggpre<<<ncnt, 256, 0, stream>>>(sCur, hidS, offs, srcS, Pbuf, Ssum, nn0);
      k_gemm_fused<<<ncnt/16, 256, 0, stream>>>(Pbuf, Bpack, Ssum, h2_b, deginv, sCur, sNxt,
                                                conv_root, conv_bias, WihT, WhhT,
                                                gru_b_ih, gru_b_hh, nn0);
    }
    float* tmp = sCur; sCur = sNxt; sNxt = tmp;
  }

  k_s2s_all<<<N_GRAPH, 256, 0, stream>>>(sCur, goff, IhT, HhT, lstm_b_ih, lstm_b_hh, ebuf,
                                         lin1_w, lin1_b, lin2_w, lin2_b, (float*)d_out);
}